// Round 2
// baseline (239.326 us; speedup 1.0000x reference)
//
#include <hip/hip_runtime.h>
#include <cstdint>

constexpr int N_FEAT  = 8;
constexpr int E_FEAT  = 4;
constexpr int NUM_IN  = 2 * (N_FEAT + 2) + E_FEAT + 1;  // 25
constexpr int NUM_OUT = 2 * N_FEAT + E_FEAT;            // 20
constexpr int BLK     = 256;
constexpr int EPT     = 2;   // edges per thread

// Load the 25 fp32 input features for edge e (coalesced, vectorized).
__device__ __forceinline__ void load_x(
    int e,
    const float* __restrict__ r,
    const float* __restrict__ a_data,
    const float* __restrict__ a_mat,
    const float* __restrict__ a_inf,
    const float* __restrict__ b_data,
    const float* __restrict__ b_mat,
    const float* __restrict__ b_inf,
    const float* __restrict__ e_data,
    float x[NUM_IN]) {
  const float4* a4 = reinterpret_cast<const float4*>(a_data) + 2 * (size_t)e;
  const float4* b4 = reinterpret_cast<const float4*>(b_data) + 2 * (size_t)e;
  float4 a0 = a4[0], a1 = a4[1];
  float4 b0 = b4[0], b1v = b4[1];
  float4 ev = reinterpret_cast<const float4*>(e_data)[e];
  x[0]  = r[e];
  x[1]  = a0.x; x[2]  = a0.y; x[3]  = a0.z; x[4]  = a0.w;
  x[5]  = a1.x; x[6]  = a1.y; x[7]  = a1.z; x[8]  = a1.w;
  x[9]  = a_mat[e];
  x[10] = a_inf[e];
  x[11] = b0.x; x[12] = b0.y; x[13] = b0.z; x[14] = b0.w;
  x[15] = b1v.x; x[16] = b1v.y; x[17] = b1v.z; x[18] = b1v.w;
  x[19] = b_mat[e];
  x[20] = b_inf[e];
  x[21] = ev.x; x[22] = ev.y; x[23] = ev.z; x[24] = ev.w;
}

__device__ __forceinline__ void store_y(int e, int E, float* __restrict__ out,
                                        const float y[NUM_OUT]) {
  float4* o0 = reinterpret_cast<float4*>(out) + 2 * (size_t)e;            // (E,8)
  o0[0] = make_float4(y[0], y[1], y[2],  y[3]);
  o0[1] = make_float4(y[4], y[5], y[6],  y[7]);
  float4* o1 = reinterpret_cast<float4*>(out + (size_t)8 * E) + 2 * (size_t)e;  // (E,8)
  o1[0] = make_float4(y[8],  y[9],  y[10], y[11]);
  o1[1] = make_float4(y[12], y[13], y[14], y[15]);
  reinterpret_cast<float4*>(out + (size_t)16 * E)[e] =                    // (E,4)
      make_float4(y[16], y[17], y[18], y[19]);
}

// EPT=2: each wave-uniform weight (SGPR) feeds two independent FMA chains,
// halving the weight-fetch latency exposure per FLOP and doubling per-thread
// ILP. Peak liveness: x0+x1 (50) + h0+h1 (50) ~= 110 VGPR, inside the
// 128-VGPR budget that amdgpu_waves_per_eu(4,4) pins. The (4,4) pin is
// load-bearing: without it the allocator chased 8 waves/EU and spilled
// x/h to scratch (76 us, VMEM-bound at EPT=1).
__global__ __launch_bounds__(BLK)
__attribute__((amdgpu_waves_per_eu(4, 4)))
void edge_mlp(
    const float* __restrict__ r,
    const float* __restrict__ a_data,
    const float* __restrict__ a_mat,
    const float* __restrict__ a_inf,
    const float* __restrict__ b_data,
    const float* __restrict__ b_mat,
    const float* __restrict__ b_inf,
    const float* __restrict__ e_data,
    const float* __restrict__ W1,   // (25,25) row-major fp32
    const float* __restrict__ B1,   // (25,)
    const float* __restrict__ W2,   // (20,25) row-major
    const float* __restrict__ B2,   // (20,)
    float*       __restrict__ out,  // fp32, 3 segments concatenated
    int E) {
  const int tid  = threadIdx.x;
  const int base = blockIdx.x * (BLK * EPT);
  const int e0   = base + tid;
  const int e1   = base + BLK + tid;
  if (e0 >= E) return;
  const bool p1  = (e1 < E);
  const int e1c  = p1 ? e1 : e0;   // clamp so the tail block's loads stay in-bounds

  // ---- gather features for both edges ----
  float x0[NUM_IN], x1[NUM_IN];
  load_x(e0,  r, a_data, a_mat, a_inf, b_data, b_mat, b_inf, e_data, x0);
  load_x(e1c, r, a_data, a_mat, a_inf, b_data, b_mat, b_inf, e_data, x1);

  // ---- layer 1: h = relu(W1 @ x + b1); one SGPR weight -> two FMA chains ----
  float h0[NUM_IN], h1[NUM_IN];
#pragma unroll
  for (int j = 0; j < NUM_IN; ++j) {
    const float* wr = W1 + j * NUM_IN;
    float acc0 = B1[j];
    float acc1 = acc0;
#pragma unroll
    for (int k = 0; k < NUM_IN; ++k) {
      const float w = wr[k];
      acc0 = fmaf(w, x0[k], acc0);
      acc1 = fmaf(w, x1[k], acc1);
    }
    h0[j] = fmaxf(acc0, 0.0f);
    h1[j] = fmaxf(acc1, 0.0f);
  }

  // ---- layer 2: y = relu(W2 @ h + b2) ----
  float y0[NUM_OUT], y1[NUM_OUT];
#pragma unroll
  for (int j = 0; j < NUM_OUT; ++j) {
    const float* wr = W2 + j * NUM_IN;
    float acc0 = B2[j];
    float acc1 = acc0;
#pragma unroll
    for (int k = 0; k < NUM_IN; ++k) {
      const float w = wr[k];
      acc0 = fmaf(w, h0[k], acc0);
      acc1 = fmaf(w, h1[k], acc1);
    }
    y0[j] = fmaxf(acc0, 0.0f);
    y1[j] = fmaxf(acc1, 0.0f);
  }

  // ---- store both edges ----
  store_y(e0, E, out, y0);
  if (p1) store_y(e1, E, out, y1);
}

extern "C" void kernel_launch(void* const* d_in, const int* in_sizes, int n_in,
                              void* d_out, int out_size, void* d_ws, size_t ws_size,
                              hipStream_t stream) {
  const float* r      = (const float*)d_in[0];
  const float* a_data = (const float*)d_in[1];
  const float* a_mat  = (const float*)d_in[2];
  const float* a_inf  = (const float*)d_in[3];
  const float* b_data = (const float*)d_in[4];
  const float* b_mat  = (const float*)d_in[5];
  const float* b_inf  = (const float*)d_in[6];
  const float* e_data = (const float*)d_in[7];
  const float* W1     = (const float*)d_in[8];
  const float* B1     = (const float*)d_in[9];
  const float* W2     = (const float*)d_in[10];
  const float* B2     = (const float*)d_in[11];
  int E = in_sizes[0];

  const int epb = BLK * EPT;  // edges per block
  edge_mlp<<<(E + epb - 1) / epb, BLK, 0, stream>>>(
      r, a_data, a_mat, a_inf, b_data, b_mat, b_inf, e_data,
      W1, B1, W2, B2, (float*)d_out, E);
}